// Round 8
// baseline (107.003 us; speedup 1.0000x reference)
//
#include <hip/hip_runtime.h>
#include <hip/hip_bf16.h>

// Problem constants
#define D_IN 1024
#define D_EMB 512
#define HIDDEN 256
#define NUM_CLASSES 64
#define N_SUPPORT 4096
#define N_QUERY 8192

typedef __bf16 bf16x8 __attribute__((ext_vector_type(8)));
typedef __bf16 bf16x4 __attribute__((ext_vector_type(4)));
typedef float f32x4 __attribute__((ext_vector_type(4)));

#define GLOAD_LDS16(g, l)                                                          \
  __builtin_amdgcn_global_load_lds(                                                \
      (const __attribute__((address_space(1))) unsigned int*)(g),                  \
      (__attribute__((address_space(3))) unsigned int*)(l), 16, 0, 0)

// Pinned-issue global load (prevents compiler sinking the load to its use):
#define GLOBAL_LOAD_F4(dst, ptr, off)                                              \
  asm volatile("global_load_dwordx4 %0, %1, off offset:" #off                      \
               : "=v"(dst) : "v"(ptr) : "memory")

// ---------------------------------------------------------------------------
// prep: both weight transposes -> bf16 [cols][rows]
//   blocks [0,512):   W_e [1024][512] -> WeT [512][1024]
//   blocks [512,640): W1[:512][256]   -> WqT [256][512]
// ---------------------------------------------------------------------------
__global__ __launch_bounds__(256) void prep(
    const float* __restrict__ W_e, const float* __restrict__ W1,
    __bf16* __restrict__ WeT, __bf16* __restrict__ WqT) {
  __shared__ float tile[32][33];
  const int tid = threadIdx.x;
  int b = blockIdx.x;
  const float* in;
  __bf16* out;
  int bx, by, rows, cols;
  if (b < 512) {
    in = W_e; out = WeT; rows = D_IN; cols = D_EMB;
    bx = (b & 15) * 32; by = (b >> 4) * 32;
  } else {
    b -= 512;
    in = W1; out = WqT; rows = D_EMB; cols = HIDDEN;  // W1[:512] only
    bx = (b & 7) * 32; by = (b >> 3) * 32;
  }
  int tx = tid & 31, ty = tid >> 5;
#pragma unroll
  for (int i = ty; i < 32; i += 8)
    tile[i][tx] = in[(long)(by + i) * cols + bx + tx];
  __syncthreads();
#pragma unroll
  for (int i = ty; i < 32; i += 8)
    out[(long)(bx + i) * rows + by + tx] = (__bf16)tile[tx][i];
}

// ---------------------------------------------------------------------------
// Fused-convert pipelined embedding GEMM:
//   emb[12288][512] = relu( [support;query](fp32) @ WeT^T + b_e ) -> bf16
// BM=128, BN=64, BK=32. A: fp32 -> regs via pinned asm loads (issued BEFORE
// compute), cvt -> swizzled ds_write_b128 AFTER compute (T14 split, counted
// vmcnt). B: global_load_lds with inverse-swizzled source (rule #21).
// One raw s_barrier per K-step; vmcnt never drained mid-phase.
// ---------------------------------------------------------------------------
__global__ __launch_bounds__(256, 4) void gemm_embf(
    const float* __restrict__ support, const float* __restrict__ query,
    const __bf16* __restrict__ BT, const float* __restrict__ bias,
    __bf16* __restrict__ C) {
  constexpr int BM = 128, BN = 64, BK = 32;
  constexpr int N = D_EMB, K = D_IN;
  constexpr int NT = K / BK;  // 32
  constexpr int MR = 4, NR = 2;

  __shared__ __align__(16) __bf16 As[2][BM * BK];  // 2 x 8 KB
  __shared__ __align__(16) __bf16 Bs[2][BN * BK];  // 2 x 4 KB

  const int tid = threadIdx.x;
  const int wave = tid >> 6, lane = tid & 63;
  const int wr = wave >> 1, wc = wave & 1;
  const int l16 = lane & 15, half = lane >> 4;
  const int slot = half ^ ((l16 >> 1) & 3);  // swizzled 16B slot for reads

  const int m0 = blockIdx.x * BM;
  const int n0 = blockIdx.y * BN;
  // grid (96, 8): same m-tile's 8 n-tiles differ by 96 in linear id; 96%8==0
  // -> same XCD -> A re-reads are L2 hits.

  // block never straddles the support/query boundary (4096 % 128 == 0)
  const float* Abase = (m0 < N_SUPPORT)
                           ? support + (long)m0 * K
                           : query + (long)(m0 - N_SUPPORT) * K;

  // A staging: thread owns row tid>>1, fp32 half (tid&1)*16
  const int arow = tid >> 1;
  const int ach = tid & 1;
  const float* aptr = Abase + (long)arow * K + ach * 16;
  const int asw = (arow >> 1) & 3;
  const int aoff0 = arow * BK + ((ach * 2) ^ asw) * 8;
  const int aoff1 = arow * BK + ((ach * 2 + 1) ^ asw) * 8;

  // B staging: linear dest, inverse-swizzled source column
  const int brow = tid >> 2;
  const int bkc = (tid & 3) ^ ((brow >> 1) & 3);
  const __bf16* bptr = BT + (long)(n0 + brow) * K + bkc * 8;

  float4 av0, av1, av2, av3;

  f32x4 acc[MR][NR];
#pragma unroll
  for (int m = 0; m < MR; ++m)
#pragma unroll
    for (int n = 0; n < NR; ++n) acc[m][n] = (f32x4)0.0f;

#define LOAD_A(t)                                                           \
  {                                                                         \
    const float* p = aptr + (t) * BK;                                       \
    GLOBAL_LOAD_F4(av0, p, 0);                                              \
    GLOBAL_LOAD_F4(av1, p, 16);                                             \
    GLOBAL_LOAD_F4(av2, p, 32);                                             \
    GLOBAL_LOAD_F4(av3, p, 48);                                             \
  }

#define GLD_B(t, buf) GLOAD_LDS16(bptr + (t) * BK, &Bs[buf][tid * 8])

#define CVT_WRITE(buf)                                                      \
  {                                                                         \
    asm volatile("s_waitcnt vmcnt(1)" ::: "memory");                        \
    __builtin_amdgcn_sched_barrier(0);                                      \
    bf16x8 o0, o1;                                                          \
    o0[0] = (__bf16)av0.x; o0[1] = (__bf16)av0.y;                           \
    o0[2] = (__bf16)av0.z; o0[3] = (__bf16)av0.w;                           \
    o0[4] = (__bf16)av1.x; o0[5] = (__bf16)av1.y;                           \
    o0[6] = (__bf16)av1.z; o0[7] = (__bf16)av1.w;                           \
    o1[0] = (__bf16)av2.x; o1[1] = (__bf16)av2.y;                           \
    o1[2] = (__bf16)av2.z; o1[3] = (__bf16)av2.w;                           \
    o1[4] = (__bf16)av3.x; o1[5] = (__bf16)av3.y;                           \
    o1[6] = (__bf16)av3.z; o1[7] = (__bf16)av3.w;                           \
    *(bf16x8*)(&As[buf][aoff0]) = o0;                                       \
    *(bf16x8*)(&As[buf][aoff1]) = o1;                                       \
  }

#define COMPUTE(buf)                                                        \
  {                                                                         \
    bf16x8 a[MR], b[NR];                                                    \
    _Pragma("unroll") for (int m = 0; m < MR; ++m)                          \
        a[m] = *(const bf16x8*)(&As[buf][(wr * 64 + m * 16 + l16) * BK +    \
                                         slot * 8]);                        \
    _Pragma("unroll") for (int n = 0; n < NR; ++n)                          \
        b[n] = *(const bf16x8*)(&Bs[buf][(wc * 32 + n * 16 + l16) * BK +    \
                                         slot * 8]);                        \
    asm volatile("s_waitcnt lgkmcnt(0)" ::: "memory");                      \
    __builtin_amdgcn_sched_barrier(0);                                      \
    _Pragma("unroll") for (int m = 0; m < MR; ++m)                          \
        _Pragma("unroll") for (int n = 0; n < NR; ++n)                      \
            acc[m][n] = __builtin_amdgcn_mfma_f32_16x16x32_bf16(            \
                a[m], b[n], acc[m][n], 0, 0, 0);                            \
  }

  // prologue: stage tile 0
  LOAD_A(0);
  GLD_B(0, 0);
  CVT_WRITE(0);  // waits vmcnt(1): A regs ready, B still in flight
  asm volatile("s_waitcnt vmcnt(0) lgkmcnt(0)" ::: "memory");
  __builtin_amdgcn_s_barrier();

  int cur = 0;
  for (int t = 0; t < NT - 1; ++t) {
    LOAD_A(t + 1);        // pinned issue: HBM latency hides under COMPUTE
    GLD_B(t + 1, cur ^ 1);
    COMPUTE(cur);
    CVT_WRITE(cur ^ 1);   // vmcnt(1): drain A(t+1); B(t+1) stays in flight
    asm volatile("s_waitcnt vmcnt(0) lgkmcnt(0)" ::: "memory");
    __builtin_amdgcn_s_barrier();
    cur ^= 1;
  }
  COMPUTE(cur);

#undef LOAD_A
#undef GLD_B
#undef CVT_WRITE
#undef COMPUTE

  // epilogue: C/D layout col = lane&15, row = (lane>>4)*4 + j  [m89/m91]
#pragma unroll
  for (int m = 0; m < MR; ++m)
#pragma unroll
    for (int n = 0; n < NR; ++n) {
      const int col = n0 + wc * 32 + n * 16 + l16;
      const float bv = bias[col];
#pragma unroll
      for (int j = 0; j < 4; ++j) {
        int row = m0 + wr * 64 + m * 16 + half * 4 + j;
        float v = fmaxf(acc[m][n][j] + bv, 0.0f);
        C[(long)row * N + col] = (__bf16)v;
      }
    }
}

// ---------------------------------------------------------------------------
// Counted-vmcnt pipelined MFMA GEMM (bf16 A), as in R7:
//   C = A[M][K] @ BT[N][K]^T + bias
// BK=32, 4 waves (2x2), 3 LDS buffers, depth-2 prefetch via global_load_lds.
// ---------------------------------------------------------------------------
template <int BM, int BN, int K, bool OUT_BF16>
__global__ __launch_bounds__(256, 4) void gemm_pipe(
    const __bf16* __restrict__ A, const __bf16* __restrict__ BT,
    const float* __restrict__ bias, void* __restrict__ Cv, int Ncols) {
  constexpr int BK = 32;
  constexpr int NT = K / BK;
  constexpr int MR = BM / 32;
  constexpr int NR = BN / 32;
  constexpr int AQ = BM * 4 / 256;
  constexpr int LOADS = AQ + 1;

  __shared__ __align__(16) __bf16 As[3][BM * BK];
  __shared__ __align__(16) __bf16 Bs[3][BN * BK];

  const int tid = threadIdx.x;
  const int wave = tid >> 6, lane = tid & 63;
  const int wr = wave >> 1, wc = wave & 1;
  const int l16 = lane & 15, half = lane >> 4;
  const int slot = half ^ ((l16 >> 1) & 3);

  const int m0 = blockIdx.x * BM;
  const int n0 = blockIdx.y * BN;

  f32x4 acc[MR][NR];
#pragma unroll
  for (int m = 0; m < MR; ++m)
#pragma unroll
    for (int n = 0; n < NR; ++n) acc[m][n] = (f32x4)0.0f;

#define STAGE(t, buf)                                                       \
  {                                                                         \
    _Pragma("unroll") for (int q = 0; q < AQ; ++q) {                        \
      int chunk = q * 256 + tid;                                            \
      int row = chunk >> 2;                                                 \
      int kc = (chunk & 3) ^ ((row >> 1) & 3);                              \
      GLOAD_LDS16(A + (long)(m0 + row) * K + (t) * BK + kc * 8,             \
                  &As[buf][chunk * 8]);                                     \
    }                                                                       \
    {                                                                       \
      int chunk = tid;                                                      \
      int row = chunk >> 2;                                                 \
      int kc = (chunk & 3) ^ ((row >> 1) & 3);                              \
      GLOAD_LDS16(BT + (long)(n0 + row) * K + (t) * BK + kc * 8,            \
                  &Bs[buf][chunk * 8]);                                     \
    }                                                                       \
  }

#define COMPUTE(buf)                                                        \
  {                                                                         \
    bf16x8 a[MR], b[NR];                                                    \
    _Pragma("unroll") for (int m = 0; m < MR; ++m)                          \
        a[m] = *(const bf16x8*)(&As[buf][(wr * (BM / 2) + m * 16 + l16) *   \
                                             BK + slot * 8]);               \
    _Pragma("unroll") for (int n = 0; n < NR; ++n)                          \
        b[n] = *(const bf16x8*)(&Bs[buf][(wc * (BN / 2) + n * 16 + l16) *   \
                                             BK + slot * 8]);               \
    asm volatile("s_waitcnt lgkmcnt(0)" ::: "memory");                      \
    __builtin_amdgcn_sched_barrier(0);                                      \
    _Pragma("unroll") for (int m = 0; m < MR; ++m)                          \
        _Pragma("unroll") for (int n = 0; n < NR; ++n)                      \
            acc[m][n] = __builtin_amdgcn_mfma_f32_16x16x32_bf16(            \
                a[m], b[n], acc[m][n], 0, 0, 0);                            \
  }

#define WAIT_PREV()                                                         \
  if constexpr (LOADS == 3) {                                               \
    asm volatile("s_waitcnt vmcnt(3)" ::: "memory");                        \
  } else {                                                                  \
    asm volatile("s_waitcnt vmcnt(2)" ::: "memory");                        \
  }

  STAGE(0, 0);
  STAGE(1, 1);
  WAIT_PREV();
  __builtin_amdgcn_s_barrier();

  int cur = 0;
  for (int t = 0; t < NT - 2; ++t) {
    int nb = cur + 2;
    if (nb >= 3) nb -= 3;
    STAGE(t + 2, nb);
    COMPUTE(cur);
    WAIT_PREV();
    __builtin_amdgcn_s_barrier();
    cur = (cur + 1 == 3) ? 0 : cur + 1;
  }
  COMPUTE(cur);
  asm volatile("s_waitcnt vmcnt(0)" ::: "memory");
  __builtin_amdgcn_s_barrier();
  cur = (cur + 1 == 3) ? 0 : cur + 1;
  COMPUTE(cur);

#undef STAGE
#undef COMPUTE
#undef WAIT_PREV

#pragma unroll
  for (int m = 0; m < MR; ++m)
#pragma unroll
    for (int n = 0; n < NR; ++n) {
      const int col = n0 + wc * (BN / 2) + n * 16 + l16;
      const float bv = bias[col];
#pragma unroll
      for (int j = 0; j < 4; ++j) {
        int row = m0 + wr * (BM / 2) + m * 16 + half * 4 + j;
        float v = acc[m][n][j] + bv;
        if (OUT_BF16) {
          v = fmaxf(v, 0.0f);
          ((__bf16*)Cv)[(long)row * Ncols + col] = (__bf16)v;
        } else {
          ((float*)Cv)[(long)row * Ncols + col] = v;
        }
      }
    }
}

// ---------------------------------------------------------------------------
// class partial sums, no atomics / no zero-init. grid (64 classes, 8 slices).
// ---------------------------------------------------------------------------
__global__ __launch_bounds__(256) void proto_partial(
    const __bf16* __restrict__ s_emb, const int* __restrict__ labels,
    float* __restrict__ sums_part, int* __restrict__ cnt_part) {
  const int c = blockIdx.x;
  const int s = blockIdx.y;  // 0..7
  const int tid = threadIdx.x;
  const int j0 = s * (N_SUPPORT / 8);
  float a0 = 0.0f, a1 = 0.0f;
  int count = 0;
#pragma unroll 4
  for (int j = j0; j < j0 + N_SUPPORT / 8; j += 4) {
    int4 lab4 = *(const int4*)(labels + j);
#pragma unroll
    for (int u = 0; u < 4; ++u) {
      int lab = (u == 0) ? lab4.x : (u == 1) ? lab4.y : (u == 2) ? lab4.z : lab4.w;
      if (lab == c) {
        const __bf16* r = s_emb + (long)(j + u) * D_EMB;
        a0 += (float)r[tid];
        a1 += (float)r[tid + 256];
        ++count;
      }
    }
  }
  float* dst = sums_part + (long)(c * 8 + s) * D_EMB;
  dst[tid] = a0;
  dst[tid + 256] = a1;
  if (tid == 0) cnt_part[c * 8 + s] = count;
}

// ---------------------------------------------------------------------------
// cpb_part[kc][c][n] = sum_{k in chunk kc} means[c][k] * W1[(D_EMB+k)][n]
// grid (64, 4). b1 folded into qp GEMM bias. Summed in score staging.
// ---------------------------------------------------------------------------
__global__ __launch_bounds__(256) void proto_cpb(
    const float* __restrict__ sums_part, const int* __restrict__ cnt_part,
    const float* __restrict__ W1, float* __restrict__ cpb_part) {
  __shared__ float ls[128];
  const int c = blockIdx.x;
  const int kc = blockIdx.y;
  const int k0 = kc * 128;
  const int tid = threadIdx.x;

  int nc = 0;
#pragma unroll
  for (int s = 0; s < 8; ++s) nc += cnt_part[c * 8 + s];
  float inv = 1.0f / fmaxf((float)nc, 1.0f);

  if (tid < 128) {
    float v = 0.0f;
#pragma unroll
    for (int s = 0; s < 8; ++s)
      v += sums_part[(long)(c * 8 + s) * D_EMB + k0 + tid];
    ls[tid] = v * inv;
  }
  __syncthreads();

  float acc = 0.0f;
#pragma unroll 8
  for (int k = 0; k < 128; ++k)
    acc = fmaf(ls[k], W1[(long)(D_EMB + k0 + k) * HIDDEN + tid], acc);
  cpb_part[((long)kc * NUM_CLASSES + c) * HIDDEN + tid] = acc;
}

// ---------------------------------------------------------------------------
// fused score: out[q][c] = sigmoid( sum_k relu(qp[q,k]+cpb[c,k]) * W2[k] + b2 )
// qp already includes b1. cpb_part summed during staging.
// lane = class c; wave handles 8 q-rows; block = 4 waves = 32 q-rows.
// ---------------------------------------------------------------------------
__global__ __launch_bounds__(256) void score_kernel(
    const float* __restrict__ qp, const float* __restrict__ cpb_part,
    const float* __restrict__ W2, const float* __restrict__ b2,
    float* __restrict__ out) {
  constexpr int CPB_S = 260;  // f32 stride: 1040 B, 16B aligned
  __shared__ __align__(16) float cpb_s[NUM_CLASSES * CPB_S];
  __shared__ __align__(16) float qp_s[32 * HIDDEN];
  __shared__ __align__(16) float w2_s[HIDDEN];

  const int tid = threadIdx.x;
  const int w = tid >> 6;
  const int c = tid & 63;
  const int qb0 = blockIdx.x * 32;
  constexpr int NCH = NUM_CLASSES * HIDDEN;

  w2_s[tid] = W2[tid];
  for (int i = tid; i < NCH; i += 256)
    cpb_s[(i >> 8) * CPB_S + (i & (HIDDEN - 1))] =
        cpb_part[i] + cpb_part[NCH + i] + cpb_part[2 * NCH + i] +
        cpb_part[3 * NCH + i];
  for (int i = tid; i < 32 * HIDDEN; i += 256)
    qp_s[i] = qp[(long)qb0 * HIDDEN + i];
  __syncthreads();

  const float bb = b2[0];
  float acc[8];
#pragma unroll
  for (int q = 0; q < 8; ++q) acc[q] = 0.0f;

  const float* crow = cpb_s + c * CPB_S;
  const float* qbase = qp_s + (w * 8) * HIDDEN;

#pragma unroll 4
  for (int kc = 0; kc < HIDDEN / 4; ++kc) {
    f32x4 cv = *(const f32x4*)(crow + kc * 4);
    f32x4 wv = *(const f32x4*)(w2_s + kc * 4);
#pragma unroll
    for (int q = 0; q < 8; ++q) {
      f32x4 qv = *(const f32x4*)(qbase + q * HIDDEN + kc * 4);
      acc[q] = fmaf(fmaxf(qv[0] + cv[0], 0.0f), wv[0], acc[q]);
      acc[q] = fmaf(fmaxf(qv[1] + cv[1], 0.0f), wv[1], acc[q]);
      acc[q] = fmaf(fmaxf(qv[2] + cv[2], 0.0f), wv[2], acc[q]);
      acc[q] = fmaf(fmaxf(qv[3] + cv[3], 0.0f), wv[3], acc[q]);
    }
  }

#pragma unroll
  for (int q = 0; q < 8; ++q) {
    float x = acc[q] + bb;
    out[(long)(qb0 + w * 8 + q) * NUM_CLASSES + c] = 1.0f / (1.0f + __expf(-x));
  }
}

// ---------------------------------------------------------------------------
extern "C" void kernel_launch(void* const* d_in, const int* in_sizes, int n_in,
                              void* d_out, int out_size, void* d_ws,
                              size_t ws_size, hipStream_t stream) {
  const float* support = (const float*)d_in[0];
  const float* query   = (const float*)d_in[1];
  const int*   labels  = (const int*)d_in[2];
  const float* W_e     = (const float*)d_in[3];
  const float* b_e     = (const float*)d_in[4];
  const float* W1      = (const float*)d_in[5];
  const float* b1      = (const float*)d_in[6];
  const float* W2      = (const float*)d_in[7];
  const float* b2      = (const float*)d_in[8];
  float* out = (float*)d_out;

  char* ws = (char*)d_ws;
  size_t off = 0;
  auto alloc = [&](size_t bytes) {
    void* p = ws + off;
    off = (off + bytes + 255) & ~(size_t)255;
    return p;
  };
  const long NTOT = N_SUPPORT + N_QUERY;  // 12288
  __bf16* WeT = (__bf16*)alloc((size_t)D_EMB * D_IN * 2);           // 1 MB
  __bf16* WqT = (__bf16*)alloc((size_t)HIDDEN * D_EMB * 2);         // 256 KB
  __bf16* emb = (__bf16*)alloc((size_t)NTOT * D_EMB * 2);           // 12.6 MB
  float*  qp  = (float*)alloc((size_t)N_QUERY * HIDDEN * 4);        // 8.4 MB
  float*  sums_part = (float*)alloc((size_t)NUM_CLASSES * 8 * D_EMB * 4);
  int*    cnt_part  = (int*)alloc((size_t)NUM_CLASSES * 8 * 4);
  float*  cpb_part  = (float*)alloc((size_t)4 * NUM_CLASSES * HIDDEN * 4);

  // weight transposes only (convert now fused into gemm_embf)
  prep<<<640, 256, 0, stream>>>(W_e, W1, WeT, WqT);

  // embeddings: relu([support;query](fp32) @ W_e + b_e) -> bf16 [12288][512]
  gemm_embf<<<dim3(NTOT / 128, D_EMB / 64), 256, 0, stream>>>(
      support, query, WeT, b_e, emb);

  // class prototypes: partial sums (no atomics) -> projection parts
  proto_partial<<<dim3(NUM_CLASSES, 8), 256, 0, stream>>>(emb, labels, sums_part,
                                                          cnt_part);
  proto_cpb<<<dim3(NUM_CLASSES, 4), 256, 0, stream>>>(sums_part, cnt_part, W1,
                                                      cpb_part);

  // qp = q_emb @ Wq + b1  (f32 out [8192][256])
  gemm_pipe<64, 64, D_EMB, false>
      <<<dim3(N_QUERY / 64, HIDDEN / 64), 256, 0, stream>>>(
          emb + (long)N_SUPPORT * D_EMB, WqT, b1, qp, HIDDEN);

  // fused relation score (cpb_part summed in staging)
  score_kernel<<<N_QUERY / 32, 256, 0, stream>>>(qp, cpb_part, W2, b2, out);
}